// Round 1
// baseline (775.040 us; speedup 1.0000x reference)
//
#include <hip/hip_runtime.h>

#define NN 50000      // nodes
#define NE 800000     // edges
#define FIN 512
#define H1DIM 64
#define H2DIM 128
#define NC 10
#define NG 64

// ---------------------------------------------------------------------------
// GEMM1: xw = x[50000,512] @ [w1_l | w1_r][512,128]  (fp32, tiled LDS)
// Writes xwl[50000,64] and xwr[50000,64] separately (compact 256B rows for
// the later edge gather).
// ---------------------------------------------------------------------------
__global__ __launch_bounds__(256) void gemm1_kernel(
    const float* __restrict__ x, const float* __restrict__ wl,
    const float* __restrict__ wr, float* __restrict__ xwl,
    float* __restrict__ xwr) {
  __shared__ float As[32][36];   // 32 rows x 32 k, padded (36*4=144 B, 16B-aligned rows)
  __shared__ float Bs[32][128];  // 32 k x 128 cols

  const int tid = threadIdx.x;
  const int m0 = blockIdx.x * 32;
  const int tc = tid & 15;        // col group 0..15
  const int tr = tid >> 4;        // row group 0..15
  const int c0 = tc * 8;
  const int r0 = tr * 2;

  float acc[2][8];
#pragma unroll
  for (int i = 0; i < 2; i++)
#pragma unroll
    for (int j = 0; j < 8; j++) acc[i][j] = 0.f;

  const int arow = tid >> 3;          // 0..31
  const int akq = (tid & 7) * 4;      // 0..28
  const int agm = m0 + arow;

  for (int k0 = 0; k0 < FIN; k0 += 32) {
    // stage A tile
    float4 av = make_float4(0.f, 0.f, 0.f, 0.f);
    if (agm < NN) av = *(const float4*)(x + (size_t)agm * FIN + k0 + akq);
    *(float4*)(&As[arow][akq]) = av;
    // stage B tile (concat wl|wr rows)
#pragma unroll
    for (int i = 0; i < 4; i++) {
      int idx = tid * 4 + i;          // 0..1023
      int kk = idx >> 5;              // 0..31
      int c4 = (idx & 31) * 4;        // 0..124
      float4 bv;
      if (c4 < 64)
        bv = *(const float4*)(wl + (size_t)(k0 + kk) * 64 + c4);
      else
        bv = *(const float4*)(wr + (size_t)(k0 + kk) * 64 + (c4 - 64));
      *(float4*)(&Bs[kk][c4]) = bv;
    }
    __syncthreads();

#pragma unroll
    for (int kk = 0; kk < 32; kk++) {
      float a0 = As[r0][kk];
      float a1 = As[r0 + 1][kk];
      float4 b0 = *(const float4*)(&Bs[kk][c0]);
      float4 b1 = *(const float4*)(&Bs[kk][c0 + 4]);
      acc[0][0] = fmaf(a0, b0.x, acc[0][0]);
      acc[0][1] = fmaf(a0, b0.y, acc[0][1]);
      acc[0][2] = fmaf(a0, b0.z, acc[0][2]);
      acc[0][3] = fmaf(a0, b0.w, acc[0][3]);
      acc[0][4] = fmaf(a0, b1.x, acc[0][4]);
      acc[0][5] = fmaf(a0, b1.y, acc[0][5]);
      acc[0][6] = fmaf(a0, b1.z, acc[0][6]);
      acc[0][7] = fmaf(a0, b1.w, acc[0][7]);
      acc[1][0] = fmaf(a1, b0.x, acc[1][0]);
      acc[1][1] = fmaf(a1, b0.y, acc[1][1]);
      acc[1][2] = fmaf(a1, b0.z, acc[1][2]);
      acc[1][3] = fmaf(a1, b0.w, acc[1][3]);
      acc[1][4] = fmaf(a1, b1.x, acc[1][4]);
      acc[1][5] = fmaf(a1, b1.y, acc[1][5]);
      acc[1][6] = fmaf(a1, b1.z, acc[1][6]);
      acc[1][7] = fmaf(a1, b1.w, acc[1][7]);
    }
    __syncthreads();
  }

#pragma unroll
  for (int i = 0; i < 2; i++) {
    int gm = m0 + r0 + i;
    if (gm >= NN) continue;
    float4 v0 = make_float4(acc[i][0], acc[i][1], acc[i][2], acc[i][3]);
    float4 v1 = make_float4(acc[i][4], acc[i][5], acc[i][6], acc[i][7]);
    if (c0 < 64) {
      *(float4*)(xwl + (size_t)gm * 64 + c0) = v0;
      *(float4*)(xwl + (size_t)gm * 64 + c0 + 4) = v1;
    } else {
      *(float4*)(xwr + (size_t)gm * 64 + (c0 - 64)) = v0;
      *(float4*)(xwr + (size_t)gm * 64 + (c0 - 60)) = v1;
    }
  }
}

// ---------------------------------------------------------------------------
// in-degree histogram (float, exact for small counts)
// ---------------------------------------------------------------------------
__global__ __launch_bounds__(256) void deg_kernel(const int* __restrict__ dst,
                                                  float* __restrict__ deg) {
  int e = blockIdx.x * 256 + threadIdx.x;
  if (e < NE) atomicAdd(&deg[dst[e]], 1.0f);
}

// ---------------------------------------------------------------------------
// edge aggregation: agg[dst] += feat[src]   (one wave per edge, 64 feats)
// ---------------------------------------------------------------------------
__global__ __launch_bounds__(256) void edge_agg_kernel(
    const int* __restrict__ src, const int* __restrict__ dst,
    const float* __restrict__ feat, float* __restrict__ agg) {
  int gid = blockIdx.x * 256 + threadIdx.x;   // = e*64 + f
  int e = gid >> 6;
  int f = gid & 63;
  int s = src[e];
  int d = dst[e];
  atomicAdd(&agg[(size_t)d * 64 + f], feat[(size_t)s * 64 + f]);
}

// ---------------------------------------------------------------------------
// h1 = relu(agg/max(deg,1) + b1 + xwr)
// ---------------------------------------------------------------------------
__global__ __launch_bounds__(256) void h1_kernel(
    const float* __restrict__ agg, const float* __restrict__ deg,
    const float* __restrict__ xwr, const float* __restrict__ b1,
    float* __restrict__ h1) {
  int gid = blockIdx.x * 256 + threadIdx.x;   // = i*64 + f
  int i = gid >> 6;
  int f = gid & 63;
  float dg = fmaxf(deg[i], 1.0f);
  float v = agg[gid] / dg + b1[f] + xwr[gid];
  h1[gid] = fmaxf(v, 0.0f);
}

// ---------------------------------------------------------------------------
// pooling: per graph g (batch is sorted), poolA = mean_nodes(agg2/deg),
// poolB = mean_nodes(h1)
// ---------------------------------------------------------------------------
__global__ __launch_bounds__(256) void pool_kernel(
    const int* __restrict__ batch, const float* __restrict__ agg2,
    const float* __restrict__ h1, const float* __restrict__ deg,
    float* __restrict__ poolA, float* __restrict__ poolB) {
  int g = blockIdx.x;
  // binary search node range [lo,hi) for graph g (batch sorted)
  int l = 0, r = NN;
  while (l < r) { int m = (l + r) >> 1; if (batch[m] < g) l = m + 1; else r = m; }
  int lo = l;
  r = NN;
  while (l < r) { int m = (l + r) >> 1; if (batch[m] < g + 1) l = m + 1; else r = m; }
  int hi = l;

  int f = threadIdx.x & 63;
  int stripe = threadIdx.x >> 6;   // 0..3
  float accA = 0.f, accB = 0.f;
  for (int i = lo + stripe; i < hi; i += 4) {
    float rd = 1.0f / fmaxf(deg[i], 1.0f);
    accA = fmaf(agg2[(size_t)i * 64 + f], rd, accA);
    accB += h1[(size_t)i * 64 + f];
  }
  __shared__ float sA[4][64];
  __shared__ float sB[4][64];
  sA[stripe][f] = accA;
  sB[stripe][f] = accB;
  __syncthreads();
  if (threadIdx.x < 64) {
    float a = sA[0][f] + sA[1][f] + sA[2][f] + sA[3][f];
    float b = sB[0][f] + sB[1][f] + sB[2][f] + sB[3][f];
    float inv = 1.0f / fmaxf((float)(hi - lo), 1.0f);
    poolA[g * 64 + f] = a * inv;
    poolB[g * 64 + f] = b * inv;
  }
}

// ---------------------------------------------------------------------------
// final: pooled = poolA@w2l + poolB@w2r + b2 ; logits = pooled@wfc + bfc ;
// log_softmax.  One block per graph.
// ---------------------------------------------------------------------------
__global__ __launch_bounds__(128) void final_kernel(
    const float* __restrict__ poolA, const float* __restrict__ poolB,
    const float* __restrict__ w2l, const float* __restrict__ w2r,
    const float* __restrict__ b2, const float* __restrict__ wfc,
    const float* __restrict__ bfc, float* __restrict__ out) {
  int g = blockIdx.x;
  int j = threadIdx.x;
  __shared__ float sp[H2DIM];
  __shared__ float sl[NC];

  float v = b2[j];
  for (int k = 0; k < 64; k++) {
    float a = poolA[g * 64 + k];
    float b = poolB[g * 64 + k];
    v = fmaf(a, w2l[k * 128 + j], v);
    v = fmaf(b, w2r[k * 128 + j], v);
  }
  sp[j] = v;
  __syncthreads();
  if (j < NC) {
    float lg = bfc[j];
    for (int k = 0; k < H2DIM; k++) lg = fmaf(sp[k], wfc[k * NC + j], lg);
    sl[j] = lg;
  }
  __syncthreads();
  if (j < NC) {
    float m = -1e30f;
    for (int k = 0; k < NC; k++) m = fmaxf(m, sl[k]);
    float s = 0.f;
    for (int k = 0; k < NC; k++) s += expf(sl[k] - m);
    out[g * NC + j] = sl[j] - m - logf(s);
  }
}

extern "C" void kernel_launch(void* const* d_in, const int* in_sizes, int n_in,
                              void* d_out, int out_size, void* d_ws,
                              size_t ws_size, hipStream_t stream) {
  const float* x   = (const float*)d_in[0];
  const int* edge  = (const int*)d_in[1];
  const int* batch = (const int*)d_in[2];
  const float* w1l = (const float*)d_in[3];
  const float* b1l = (const float*)d_in[4];
  const float* w1r = (const float*)d_in[5];
  const float* w2l = (const float*)d_in[6];
  const float* b2l = (const float*)d_in[7];
  const float* w2r = (const float*)d_in[8];
  const float* wfc = (const float*)d_in[9];
  const float* bfc = (const float*)d_in[10];
  float* out = (float*)d_out;
  float* ws = (float*)d_ws;

  const int* src = edge;
  const int* dst = edge + NE;

  const size_t NF = (size_t)NN * 64;
  float* xwl  = ws;              // [NN,64]
  float* xwr  = xwl + NF;        // [NN,64]
  float* h1   = xwr + NF;        // [NN,64]
  float* agg  = h1 + NF;         // [NN,64]  (zeroed)
  float* agg2 = agg + NF;        // [NN,64]  (zeroed)
  float* deg  = agg2 + NF;       // [NN]     (zeroed)
  float* pA   = deg + NN;        // [NG,64]
  float* pB   = pA + (size_t)NG * 64;  // [NG,64]

  // zero agg, agg2, deg in one contiguous memset (graph-capture safe)
  hipMemsetAsync(agg, 0, (2 * NF + NN) * sizeof(float), stream);

  gemm1_kernel<<<(NN + 31) / 32, 256, 0, stream>>>(x, w1l, w1r, xwl, xwr);
  deg_kernel<<<(NE + 255) / 256, 256, 0, stream>>>(dst, deg);
  edge_agg_kernel<<<(NE * 64) / 256, 256, 0, stream>>>(src, dst, xwl, agg);
  h1_kernel<<<(NN * 64) / 256, 256, 0, stream>>>(agg, deg, xwr, b1l, h1);
  edge_agg_kernel<<<(NE * 64) / 256, 256, 0, stream>>>(src, dst, h1, agg2);
  pool_kernel<<<NG, 256, 0, stream>>>(batch, agg2, h1, deg, pA, pB);
  final_kernel<<<NG, 128, 0, stream>>>(pA, pB, w2l, w2r, b2l, wfc, bfc, out);
}

// Round 2
// 520.068 us; speedup vs baseline: 1.4903x; 1.4903x over previous
//
#include <hip/hip_runtime.h>

#define NN 50000      // nodes
#define NE 800000     // edges
#define FIN 512
#define H1DIM 64
#define H2DIM 128
#define NC 10
#define NG 64

typedef __attribute__((ext_vector_type(8))) short bf16x8;  // 8 bf16 (4 VGPRs)
typedef __attribute__((ext_vector_type(4))) float f32x4;

__device__ inline short f2bf(float f) {
  unsigned u = __float_as_uint(f);
  unsigned r = u + 0x7fffu + ((u >> 16) & 1u);  // RNE
  return (short)(r >> 16);
}

// ---------------------------------------------------------------------------
// wbt[n][k] = bf16( n<64 ? w1l[k][n] : w1r[k][n-64] )   [128][512] bf16
// ---------------------------------------------------------------------------
__global__ __launch_bounds__(256) void wbt_prep_kernel(
    const float* __restrict__ wl, const float* __restrict__ wr,
    short* __restrict__ wbt) {
  int idx = blockIdx.x * 256 + threadIdx.x;   // 0..65535
  int n = idx >> 9;        // 0..127
  int k = idx & 511;       // 0..511
  float v = (n < 64) ? wl[(size_t)k * 64 + n] : wr[(size_t)k * 64 + (n - 64)];
  wbt[idx] = f2bf(v);
}

// ---------------------------------------------------------------------------
// GEMM1 (MFMA bf16): [50000,512] @ [512,128] -> xwl[.,0:64], xwr[.,64:128]
// block tile 64(M)x128(N), K-step 32, 4 waves (2x2), wave tile 32x64
// ---------------------------------------------------------------------------
__global__ __launch_bounds__(256) void gemm1_mfma_kernel(
    const float* __restrict__ x, const short* __restrict__ wbt,
    float* __restrict__ xwl, float* __restrict__ xwr) {
  __shared__ short Asl[64][40];    // [m][k], stride 40 (80 B, 16B-aligned, conflict-safe)
  __shared__ short Bsl[128][40];   // [n][k]

  const int tid = threadIdx.x;
  const int wave = tid >> 6;
  const int lane = tid & 63;
  const int l15 = lane & 15;
  const int q = lane >> 4;             // 0..3
  const int mw = (wave & 1) * 32;
  const int nw = (wave >> 1) * 64;
  const int m0 = blockIdx.x * 64;

  const f32x4 z = {0.f, 0.f, 0.f, 0.f};
  f32x4 acc[2][4];
#pragma unroll
  for (int mi = 0; mi < 2; mi++)
#pragma unroll
    for (int ni = 0; ni < 4; ni++) acc[mi][ni] = z;

  // A staging coords: 4 threads/row, 8 elems each
  const int ar = tid >> 2;             // 0..63
  const int ac = (tid & 3) * 8;        // 0,8,16,24
  const int agm = m0 + ar;
  // B staging coords: 2 threads/n-row, 16 elems each
  const int bn = tid >> 1;             // 0..127
  const int bc = (tid & 1) * 16;       // 0,16

  for (int k0 = 0; k0 < FIN; k0 += 32) {
    // stage A (fp32 -> bf16)
    float4 v0 = make_float4(0.f, 0.f, 0.f, 0.f);
    float4 v1 = make_float4(0.f, 0.f, 0.f, 0.f);
    if (agm < NN) {
      const float* p = x + (size_t)agm * FIN + k0 + ac;
      v0 = *(const float4*)(p);
      v1 = *(const float4*)(p + 4);
    }
    bf16x8 apack;
    apack[0] = f2bf(v0.x); apack[1] = f2bf(v0.y);
    apack[2] = f2bf(v0.z); apack[3] = f2bf(v0.w);
    apack[4] = f2bf(v1.x); apack[5] = f2bf(v1.y);
    apack[6] = f2bf(v1.z); apack[7] = f2bf(v1.w);
    *(bf16x8*)(&Asl[ar][ac]) = apack;
    // stage B (already bf16, [n][k] layout)
    const short* bp = wbt + (size_t)bn * FIN + k0 + bc;
    *(bf16x8*)(&Bsl[bn][bc]) = *(const bf16x8*)(bp);
    *(bf16x8*)(&Bsl[bn][bc + 8]) = *(const bf16x8*)(bp + 8);
    __syncthreads();

    bf16x8 afrag[2], bfrag[4];
#pragma unroll
    for (int mi = 0; mi < 2; mi++)
      afrag[mi] = *(const bf16x8*)(&Asl[mw + mi * 16 + l15][q * 8]);
#pragma unroll
    for (int ni = 0; ni < 4; ni++)
      bfrag[ni] = *(const bf16x8*)(&Bsl[nw + ni * 16 + l15][q * 8]);
#pragma unroll
    for (int mi = 0; mi < 2; mi++)
#pragma unroll
      for (int ni = 0; ni < 4; ni++)
        acc[mi][ni] = __builtin_amdgcn_mfma_f32_16x16x32_bf16(
            afrag[mi], bfrag[ni], acc[mi][ni], 0, 0, 0);
    __syncthreads();
  }

  // epilogue: C[row][col], col = nw + ni*16 + l15; row = m0+mw+mi*16+q*4+r
#pragma unroll
  for (int mi = 0; mi < 2; mi++) {
    int row_base = m0 + mw + mi * 16 + q * 4;
#pragma unroll
    for (int ni = 0; ni < 4; ni++) {
      int col = nw + ni * 16 + l15;
      float* dstp = (col < 64) ? xwl : xwr;
      int c = col & 63;
#pragma unroll
      for (int r = 0; r < 4; r++) {
        int row = row_base + r;
        if (row < NN) dstp[(size_t)row * 64 + c] = acc[mi][ni][r];
      }
    }
  }
}

// ---------------------------------------------------------------------------
// counting sort: hist -> scan -> scatter
// ---------------------------------------------------------------------------
__global__ __launch_bounds__(256) void hist_kernel(const int* __restrict__ dst,
                                                   int* __restrict__ cnt) {
  int e = blockIdx.x * 256 + threadIdx.x;
  if (e < NE) atomicAdd(&cnt[dst[e]], 1);
}

#define SCAN_T 1024
#define SCAN_I 49
__global__ __launch_bounds__(1024) void scan_kernel(const int* __restrict__ cnt,
                                                    int* __restrict__ rowptr,
                                                    int* __restrict__ cursor) {
  __shared__ int ssum[SCAN_T];
  int t = threadIdx.x;
  int base = t * SCAN_I;
  int loc[SCAN_I];
  int s = 0;
#pragma unroll
  for (int j = 0; j < SCAN_I; j++) {
    int i = base + j;
    int v = (i < NN) ? cnt[i] : 0;
    loc[j] = s;
    s += v;
  }
  ssum[t] = s;
  __syncthreads();
  for (int off = 1; off < SCAN_T; off <<= 1) {
    int u = (t >= off) ? ssum[t - off] : 0;
    __syncthreads();
    ssum[t] += u;
    __syncthreads();
  }
  int excl = (t == 0) ? 0 : ssum[t - 1];
#pragma unroll
  for (int j = 0; j < SCAN_I; j++) {
    int i = base + j;
    if (i < NN) {
      int p = excl + loc[j];
      rowptr[i] = p;
      cursor[i] = p;
    }
  }
  if (t == 0) rowptr[NN] = NE;
}

__global__ __launch_bounds__(256) void scatter_kernel(
    const int* __restrict__ src, const int* __restrict__ dst,
    int* __restrict__ cursor, int* __restrict__ ssrc) {
  int e = blockIdx.x * 256 + threadIdx.x;
  if (e < NE) {
    int p = atomicAdd(&cursor[dst[e]], 1);
    ssrc[p] = src[e];
  }
}

// ---------------------------------------------------------------------------
// agg1 + h1 fused: h1[i] = relu( mean_{s in N(i)} xwl[s] + b1 + xwr[i] )
// one wave per node, lane = feature
// ---------------------------------------------------------------------------
__global__ __launch_bounds__(256) void agg1_h1_kernel(
    const int* __restrict__ rowptr, const int* __restrict__ ssrc,
    const float* __restrict__ xwl, const float* __restrict__ xwr,
    const float* __restrict__ b1, float* __restrict__ h1) {
  int node = blockIdx.x * 4 + (threadIdx.x >> 6);
  int f = threadIdx.x & 63;
  if (node >= NN) return;
  int lo = rowptr[node], hi = rowptr[node + 1];
  float acc = 0.f;
  int e = lo;
  for (; e + 4 <= hi; e += 4) {
    int s0 = ssrc[e], s1 = ssrc[e + 1], s2 = ssrc[e + 2], s3 = ssrc[e + 3];
    float a0 = xwl[(size_t)s0 * 64 + f];
    float a1 = xwl[(size_t)s1 * 64 + f];
    float a2 = xwl[(size_t)s2 * 64 + f];
    float a3 = xwl[(size_t)s3 * 64 + f];
    acc += a0 + a1 + a2 + a3;
  }
  for (; e < hi; e++) acc += xwl[(size_t)ssrc[e] * 64 + f];
  float dg = fmaxf((float)(hi - lo), 1.0f);
  float v = acc / dg + b1[f] + xwr[(size_t)node * 64 + f];
  h1[(size_t)node * 64 + f] = fmaxf(v, 0.f);
}

// ---------------------------------------------------------------------------
// agg2: agg2[i] = sum_{s in N(i)} h1[s]
// ---------------------------------------------------------------------------
__global__ __launch_bounds__(256) void agg2_kernel(
    const int* __restrict__ rowptr, const int* __restrict__ ssrc,
    const float* __restrict__ h1, float* __restrict__ agg2) {
  int node = blockIdx.x * 4 + (threadIdx.x >> 6);
  int f = threadIdx.x & 63;
  if (node >= NN) return;
  int lo = rowptr[node], hi = rowptr[node + 1];
  float acc = 0.f;
  int e = lo;
  for (; e + 4 <= hi; e += 4) {
    int s0 = ssrc[e], s1 = ssrc[e + 1], s2 = ssrc[e + 2], s3 = ssrc[e + 3];
    float a0 = h1[(size_t)s0 * 64 + f];
    float a1 = h1[(size_t)s1 * 64 + f];
    float a2 = h1[(size_t)s2 * 64 + f];
    float a3 = h1[(size_t)s3 * 64 + f];
    acc += a0 + a1 + a2 + a3;
  }
  for (; e < hi; e++) acc += h1[(size_t)ssrc[e] * 64 + f];
  agg2[(size_t)node * 64 + f] = acc;
}

// ---------------------------------------------------------------------------
// pooling: poolA = mean_nodes(agg2/deg), poolB = mean_nodes(h1)
// ---------------------------------------------------------------------------
__global__ __launch_bounds__(256) void pool_kernel(
    const int* __restrict__ batch, const float* __restrict__ agg2,
    const float* __restrict__ h1, const int* __restrict__ rowptr,
    float* __restrict__ poolA, float* __restrict__ poolB) {
  int g = blockIdx.x;
  int l = 0, r = NN;
  while (l < r) { int m = (l + r) >> 1; if (batch[m] < g) l = m + 1; else r = m; }
  int lo = l;
  r = NN;
  while (l < r) { int m = (l + r) >> 1; if (batch[m] < g + 1) l = m + 1; else r = m; }
  int hi = l;

  int f = threadIdx.x & 63;
  int stripe = threadIdx.x >> 6;
  float accA = 0.f, accB = 0.f;
  for (int i = lo + stripe; i < hi; i += 4) {
    float rd = 1.0f / fmaxf((float)(rowptr[i + 1] - rowptr[i]), 1.0f);
    accA = fmaf(agg2[(size_t)i * 64 + f], rd, accA);
    accB += h1[(size_t)i * 64 + f];
  }
  __shared__ float sA[4][64];
  __shared__ float sB[4][64];
  sA[stripe][f] = accA;
  sB[stripe][f] = accB;
  __syncthreads();
  if (threadIdx.x < 64) {
    float a = sA[0][f] + sA[1][f] + sA[2][f] + sA[3][f];
    float b = sB[0][f] + sB[1][f] + sB[2][f] + sB[3][f];
    float inv = 1.0f / fmaxf((float)(hi - lo), 1.0f);
    poolA[g * 64 + f] = a * inv;
    poolB[g * 64 + f] = b * inv;
  }
}

// ---------------------------------------------------------------------------
// final: pooled = poolA@w2l + poolB@w2r + b2 ; logits = pooled@wfc + bfc ;
// log_softmax. One block per graph.
// ---------------------------------------------------------------------------
__global__ __launch_bounds__(128) void final_kernel(
    const float* __restrict__ poolA, const float* __restrict__ poolB,
    const float* __restrict__ w2l, const float* __restrict__ w2r,
    const float* __restrict__ b2, const float* __restrict__ wfc,
    const float* __restrict__ bfc, float* __restrict__ out) {
  int g = blockIdx.x;
  int j = threadIdx.x;
  __shared__ float sp[H2DIM];
  __shared__ float sl[NC];

  float v = b2[j];
  for (int k = 0; k < 64; k++) {
    float a = poolA[g * 64 + k];
    float b = poolB[g * 64 + k];
    v = fmaf(a, w2l[k * 128 + j], v);
    v = fmaf(b, w2r[k * 128 + j], v);
  }
  sp[j] = v;
  __syncthreads();
  if (j < NC) {
    float lg = bfc[j];
    for (int k = 0; k < H2DIM; k++) lg = fmaf(sp[k], wfc[k * NC + j], lg);
    sl[j] = lg;
  }
  __syncthreads();
  if (j < NC) {
    float m = -1e30f;
    for (int k = 0; k < NC; k++) m = fmaxf(m, sl[k]);
    float s = 0.f;
    for (int k = 0; k < NC; k++) s += expf(sl[k] - m);
    out[g * NC + j] = sl[j] - m - logf(s);
  }
}

extern "C" void kernel_launch(void* const* d_in, const int* in_sizes, int n_in,
                              void* d_out, int out_size, void* d_ws,
                              size_t ws_size, hipStream_t stream) {
  const float* x   = (const float*)d_in[0];
  const int* edge  = (const int*)d_in[1];
  const int* batch = (const int*)d_in[2];
  const float* w1l = (const float*)d_in[3];
  const float* b1l = (const float*)d_in[4];
  const float* w1r = (const float*)d_in[5];
  const float* w2l = (const float*)d_in[6];
  const float* b2l = (const float*)d_in[7];
  const float* w2r = (const float*)d_in[8];
  const float* wfc = (const float*)d_in[9];
  const float* bfc = (const float*)d_in[10];
  float* out = (float*)d_out;

  const int* src = edge;
  const int* dst = edge + NE;

  const size_t NF = (size_t)NN * 64;
  float* fws  = (float*)d_ws;
  float* xwl  = fws;                   // [NN,64]
  float* xwr  = xwl + NF;              // [NN,64]
  float* h1   = xwr + NF;              // [NN,64]
  float* agg2 = h1 + NF;               // [NN,64]
  float* pA   = agg2 + NF;             // [NG,64]
  float* pB   = pA + (size_t)NG * 64;  // [NG,64]
  int* iws    = (int*)(pB + (size_t)NG * 64);
  int* cnt    = iws;                   // [NN]   (zeroed)
  int* cursor = cnt + NN;              // [NN]
  int* rowptr = cursor + NN;           // [NN+1] padded to 50004
  int* ssrc   = rowptr + 50004;        // [NE]
  short* wbt  = (short*)(ssrc + NE);   // [128][512] bf16

  hipMemsetAsync(cnt, 0, NN * sizeof(int), stream);

  hist_kernel<<<(NE + 255) / 256, 256, 0, stream>>>(dst, cnt);
  scan_kernel<<<1, SCAN_T, 0, stream>>>(cnt, rowptr, cursor);
  scatter_kernel<<<(NE + 255) / 256, 256, 0, stream>>>(src, dst, cursor, ssrc);

  wbt_prep_kernel<<<65536 / 256, 256, 0, stream>>>(w1l, w1r, wbt);
  gemm1_mfma_kernel<<<(NN + 63) / 64, 256, 0, stream>>>(x, wbt, xwl, xwr);

  agg1_h1_kernel<<<(NN + 3) / 4, 256, 0, stream>>>(rowptr, ssrc, xwl, xwr, b1l, h1);
  agg2_kernel<<<(NN + 3) / 4, 256, 0, stream>>>(rowptr, ssrc, h1, agg2);
  pool_kernel<<<NG, 256, 0, stream>>>(batch, agg2, h1, rowptr, pA, pB);
  final_kernel<<<NG, 128, 0, stream>>>(pA, pB, w2l, w2r, b2l, wfc, bfc, out);
}

// Round 3
// 372.434 us; speedup vs baseline: 2.0810x; 1.3964x over previous
//
#include <hip/hip_runtime.h>

#define NN 50000      // nodes
#define NE 800000     // edges
#define FIN 512
#define H1DIM 64
#define H2DIM 128
#define NC 10
#define NG 64

typedef __attribute__((ext_vector_type(8))) short bf16x8;  // 8 bf16 (4 VGPRs)
typedef __attribute__((ext_vector_type(4))) float f32x4;

__device__ inline short f2bf(float f) {
  unsigned u = __float_as_uint(f);
  unsigned r = u + 0x7fffu + ((u >> 16) & 1u);  // RNE
  return (short)(r >> 16);
}
__device__ inline float bf2f(short s) {
  return __uint_as_float(((unsigned)(unsigned short)s) << 16);
}

// ---------------------------------------------------------------------------
// wbt[n][k] = bf16( n<64 ? w1l[k][n] : w1r[k][n-64] )   [128][512] bf16
// ---------------------------------------------------------------------------
__global__ __launch_bounds__(256) void wbt_prep_kernel(
    const float* __restrict__ wl, const float* __restrict__ wr,
    short* __restrict__ wbt) {
  int idx = blockIdx.x * 256 + threadIdx.x;   // 0..65535
  int n = idx >> 9;        // 0..127
  int k = idx & 511;       // 0..511
  float v = (n < 64) ? wl[(size_t)k * 64 + n] : wr[(size_t)k * 64 + (n - 64)];
  wbt[idx] = f2bf(v);
}

// ---------------------------------------------------------------------------
// GEMM1 (MFMA bf16): [50000,512] @ [512,128] -> xwl(bf16)[.,0:64],
// xwr(f32)[.,64:128].  block tile 64x128, K-step 32, 4 waves, wave 32x64
// ---------------------------------------------------------------------------
__global__ __launch_bounds__(256) void gemm1_mfma_kernel(
    const float* __restrict__ x, const short* __restrict__ wbt,
    short* __restrict__ xwl, float* __restrict__ xwr) {
  __shared__ short Asl[64][40];    // [m][k], stride 40 shorts (80 B)
  __shared__ short Bsl[128][40];   // [n][k]

  const int tid = threadIdx.x;
  const int wave = tid >> 6;
  const int lane = tid & 63;
  const int l15 = lane & 15;
  const int q = lane >> 4;             // 0..3
  const int mw = (wave & 1) * 32;
  const int nw = (wave >> 1) * 64;
  const int m0 = blockIdx.x * 64;

  const f32x4 z = {0.f, 0.f, 0.f, 0.f};
  f32x4 acc[2][4];
#pragma unroll
  for (int mi = 0; mi < 2; mi++)
#pragma unroll
    for (int ni = 0; ni < 4; ni++) acc[mi][ni] = z;

  const int ar = tid >> 2;             // 0..63
  const int ac = (tid & 3) * 8;        // 0,8,16,24
  const int agm = m0 + ar;
  const int bn = tid >> 1;             // 0..127
  const int bc = (tid & 1) * 16;       // 0,16

  for (int k0 = 0; k0 < FIN; k0 += 32) {
    float4 v0 = make_float4(0.f, 0.f, 0.f, 0.f);
    float4 v1 = make_float4(0.f, 0.f, 0.f, 0.f);
    if (agm < NN) {
      const float* p = x + (size_t)agm * FIN + k0 + ac;
      v0 = *(const float4*)(p);
      v1 = *(const float4*)(p + 4);
    }
    bf16x8 apack;
    apack[0] = f2bf(v0.x); apack[1] = f2bf(v0.y);
    apack[2] = f2bf(v0.z); apack[3] = f2bf(v0.w);
    apack[4] = f2bf(v1.x); apack[5] = f2bf(v1.y);
    apack[6] = f2bf(v1.z); apack[7] = f2bf(v1.w);
    *(bf16x8*)(&Asl[ar][ac]) = apack;
    const short* bp = wbt + (size_t)bn * FIN + k0 + bc;
    *(bf16x8*)(&Bsl[bn][bc]) = *(const bf16x8*)(bp);
    *(bf16x8*)(&Bsl[bn][bc + 8]) = *(const bf16x8*)(bp + 8);
    __syncthreads();

    bf16x8 afrag[2], bfrag[4];
#pragma unroll
    for (int mi = 0; mi < 2; mi++)
      afrag[mi] = *(const bf16x8*)(&Asl[mw + mi * 16 + l15][q * 8]);
#pragma unroll
    for (int ni = 0; ni < 4; ni++)
      bfrag[ni] = *(const bf16x8*)(&Bsl[nw + ni * 16 + l15][q * 8]);
#pragma unroll
    for (int mi = 0; mi < 2; mi++)
#pragma unroll
      for (int ni = 0; ni < 4; ni++)
        acc[mi][ni] = __builtin_amdgcn_mfma_f32_16x16x32_bf16(
            afrag[mi], bfrag[ni], acc[mi][ni], 0, 0, 0);
    __syncthreads();
  }

  // epilogue: C[row][col], col = nw+ni*16+l15; row = m0+mw+mi*16+q*4+r
#pragma unroll
  for (int mi = 0; mi < 2; mi++) {
    int row_base = m0 + mw + mi * 16 + q * 4;
#pragma unroll
    for (int ni = 0; ni < 4; ni++) {
      int col = nw + ni * 16 + l15;
      int c = col & 63;
#pragma unroll
      for (int r = 0; r < 4; r++) {
        int row = row_base + r;
        if (row < NN) {
          if (col < 64) xwl[(size_t)row * 64 + c] = f2bf(acc[mi][ni][r]);
          else          xwr[(size_t)row * 64 + c] = acc[mi][ni][r];
        }
      }
    }
  }
}

// ---------------------------------------------------------------------------
// counting sort: hist -> multi-block scan -> scatter
// ---------------------------------------------------------------------------
__global__ __launch_bounds__(256) void hist_kernel(const int* __restrict__ dst,
                                                   int* __restrict__ cnt) {
  int e = blockIdx.x * 256 + threadIdx.x;
  if (e < NE) atomicAdd(&cnt[dst[e]], 1);
}

#define SCAN_BLOCKS 196   // ceil(50000/256)

__global__ __launch_bounds__(256) void scan1_kernel(const int* __restrict__ cnt,
                                                    int* __restrict__ excl,
                                                    int* __restrict__ bsum) {
  __shared__ int s[256];
  int t = threadIdx.x;
  int i = blockIdx.x * 256 + t;
  int v = (i < NN) ? cnt[i] : 0;
  s[t] = v;
  __syncthreads();
  for (int off = 1; off < 256; off <<= 1) {
    int u = (t >= off) ? s[t - off] : 0;
    __syncthreads();
    s[t] += u;
    __syncthreads();
  }
  if (i < NN) excl[i] = s[t] - v;       // exclusive within block
  if (t == 255) bsum[blockIdx.x] = s[255];
}

__global__ __launch_bounds__(256) void scan2_kernel(int* __restrict__ bsum) {
  __shared__ int s[256];
  int t = threadIdx.x;
  int v = (t < SCAN_BLOCKS) ? bsum[t] : 0;
  s[t] = v;
  __syncthreads();
  for (int off = 1; off < 256; off <<= 1) {
    int u = (t >= off) ? s[t - off] : 0;
    __syncthreads();
    s[t] += u;
    __syncthreads();
  }
  bsum[t] = s[t] - v;                    // exclusive block offsets
}

__global__ __launch_bounds__(256) void scan3_kernel(const int* __restrict__ bsum,
                                                    int* __restrict__ rowptr,
                                                    int* __restrict__ cursor) {
  int t = threadIdx.x;
  int i = blockIdx.x * 256 + t;
  if (i < NN) {
    int p = rowptr[i] + bsum[blockIdx.x];
    rowptr[i] = p;
    cursor[i] = p;
  }
  if (i == 0) rowptr[NN] = NE;
}

__global__ __launch_bounds__(256) void scatter_kernel(
    const int* __restrict__ src, const int* __restrict__ dst,
    int* __restrict__ cursor, int* __restrict__ ssrc) {
  int e = blockIdx.x * 256 + threadIdx.x;
  if (e < NE) {
    int p = atomicAdd(&cursor[dst[e]], 1);
    ssrc[p] = src[e];
  }
}

// ---------------------------------------------------------------------------
// agg1 + h1 fused: h1 = relu(mean_{s in N(i)} xwl[s] + b1 + xwr[i])  (bf16 out)
// one wave per node; 8 chunk-lanes x 8 edge-slots, 16B gathers
// ---------------------------------------------------------------------------
__global__ __launch_bounds__(256) void agg1_h1_kernel(
    const int* __restrict__ rowptr, const int* __restrict__ ssrc,
    const short* __restrict__ xwl, const float* __restrict__ xwr,
    const float* __restrict__ b1, short* __restrict__ h1) {
  int node = blockIdx.x * 4 + (threadIdx.x >> 6);
  if (node >= NN) return;
  int lane = threadIdx.x & 63;
  int c = lane & 7;        // feature chunk (8 bf16 = 16 B)
  int r = lane >> 3;       // edge slot 0..7
  int lo = rowptr[node], hi = rowptr[node + 1];
  float acc[8];
#pragma unroll
  for (int k = 0; k < 8; k++) acc[k] = 0.f;
  for (int e = lo + r; e < hi; e += 8) {
    int s = ssrc[e];
    bf16x8 v = *(const bf16x8*)(xwl + (size_t)s * 64 + c * 8);
#pragma unroll
    for (int k = 0; k < 8; k++) acc[k] += bf2f(v[k]);
  }
#pragma unroll
  for (int k = 0; k < 8; k++) {
    acc[k] += __shfl_xor(acc[k], 8);
    acc[k] += __shfl_xor(acc[k], 16);
    acc[k] += __shfl_xor(acc[k], 32);
  }
  if (r == 0) {
    float dg = fmaxf((float)(hi - lo), 1.0f);
    const float* xr = xwr + (size_t)node * 64 + c * 8;
    bf16x8 out;
#pragma unroll
    for (int k = 0; k < 8; k++) {
      float v = acc[k] / dg + b1[c * 8 + k] + xr[k];
      out[k] = f2bf(fmaxf(v, 0.f));
    }
    *(bf16x8*)(h1 + (size_t)node * 64 + c * 8) = out;
  }
}

// ---------------------------------------------------------------------------
// agg2: agg2[i] = sum_{s in N(i)} h1[s]   (f32 out)
// ---------------------------------------------------------------------------
__global__ __launch_bounds__(256) void agg2_kernel(
    const int* __restrict__ rowptr, const int* __restrict__ ssrc,
    const short* __restrict__ h1, float* __restrict__ agg2) {
  int node = blockIdx.x * 4 + (threadIdx.x >> 6);
  if (node >= NN) return;
  int lane = threadIdx.x & 63;
  int c = lane & 7;
  int r = lane >> 3;
  int lo = rowptr[node], hi = rowptr[node + 1];
  float acc[8];
#pragma unroll
  for (int k = 0; k < 8; k++) acc[k] = 0.f;
  for (int e = lo + r; e < hi; e += 8) {
    int s = ssrc[e];
    bf16x8 v = *(const bf16x8*)(h1 + (size_t)s * 64 + c * 8);
#pragma unroll
    for (int k = 0; k < 8; k++) acc[k] += bf2f(v[k]);
  }
#pragma unroll
  for (int k = 0; k < 8; k++) {
    acc[k] += __shfl_xor(acc[k], 8);
    acc[k] += __shfl_xor(acc[k], 16);
    acc[k] += __shfl_xor(acc[k], 32);
  }
  if (r == 0) {
    float* p = agg2 + (size_t)node * 64 + c * 8;
    f32x4 lo4 = {acc[0], acc[1], acc[2], acc[3]};
    f32x4 hi4 = {acc[4], acc[5], acc[6], acc[7]};
    *(f32x4*)(p) = lo4;
    *(f32x4*)(p + 4) = hi4;
  }
}

// ---------------------------------------------------------------------------
// pool phase1: run-length accumulate (batch sorted) + atomic flush
// thread: chunk c = t&15 (float4 of feats), slice s = t>>4 (16 nodes each)
// ---------------------------------------------------------------------------
__global__ __launch_bounds__(256) void pool1_kernel(
    const int* __restrict__ batch, const float* __restrict__ agg2,
    const short* __restrict__ h1, const int* __restrict__ rowptr,
    float* __restrict__ poolA, float* __restrict__ poolB,
    float* __restrict__ poolCnt) {
  int t = threadIdx.x;
  int c = t & 15;
  int s = t >> 4;
  int n0 = blockIdx.x * 256 + s * 16;
  int n1 = n0 + 16;
  if (n1 > NN) n1 = NN;

  f32x4 aA = {0.f, 0.f, 0.f, 0.f};
  f32x4 aB = {0.f, 0.f, 0.f, 0.f};
  int cur_g = -1;
  float run = 0.f;
  for (int n = n0; n < n1; n++) {
    int g = batch[n];
    if (g != cur_g) {
      if (cur_g >= 0) {
        float* pa = poolA + (size_t)cur_g * 64 + c * 4;
        float* pb = poolB + (size_t)cur_g * 64 + c * 4;
#pragma unroll
        for (int k = 0; k < 4; k++) {
          atomicAdd(&pa[k], aA[k]);
          atomicAdd(&pb[k], aB[k]);
        }
        if (c == 0) atomicAdd(&poolCnt[cur_g], run);
      }
      cur_g = g;
      aA = (f32x4){0.f, 0.f, 0.f, 0.f};
      aB = (f32x4){0.f, 0.f, 0.f, 0.f};
      run = 0.f;
    }
    float rd = 1.0f / fmaxf((float)(rowptr[n + 1] - rowptr[n]), 1.0f);
    f32x4 a2 = *(const f32x4*)(agg2 + (size_t)n * 64 + c * 4);
    const short* hp = h1 + (size_t)n * 64 + c * 4;
#pragma unroll
    for (int k = 0; k < 4; k++) {
      aA[k] = fmaf(a2[k], rd, aA[k]);
      aB[k] += bf2f(hp[k]);
    }
    run += 1.f;
  }
  if (cur_g >= 0) {
    float* pa = poolA + (size_t)cur_g * 64 + c * 4;
    float* pb = poolB + (size_t)cur_g * 64 + c * 4;
#pragma unroll
    for (int k = 0; k < 4; k++) {
      atomicAdd(&pa[k], aA[k]);
      atomicAdd(&pb[k], aB[k]);
    }
    if (c == 0) atomicAdd(&poolCnt[cur_g], run);
  }
}

// ---------------------------------------------------------------------------
// final: pooled = (poolA/cnt)@w2l + (poolB/cnt)@w2r + b2 ; @wfc + bfc ;
// log_softmax. One block per graph.
// ---------------------------------------------------------------------------
__global__ __launch_bounds__(128) void final_kernel(
    const float* __restrict__ poolA, const float* __restrict__ poolB,
    const float* __restrict__ poolCnt, const float* __restrict__ w2l,
    const float* __restrict__ w2r, const float* __restrict__ b2,
    const float* __restrict__ wfc, const float* __restrict__ bfc,
    float* __restrict__ out) {
  int g = blockIdx.x;
  int j = threadIdx.x;
  __shared__ float sp[H2DIM];
  __shared__ float sl[NC];

  float invc = 1.0f / fmaxf(poolCnt[g], 1.0f);
  float v = b2[j];
  for (int k = 0; k < 64; k++) {
    float a = poolA[g * 64 + k] * invc;
    float b = poolB[g * 64 + k] * invc;
    v = fmaf(a, w2l[k * 128 + j], v);
    v = fmaf(b, w2r[k * 128 + j], v);
  }
  sp[j] = v;
  __syncthreads();
  if (j < NC) {
    float lg = bfc[j];
    for (int k = 0; k < H2DIM; k++) lg = fmaf(sp[k], wfc[k * NC + j], lg);
    sl[j] = lg;
  }
  __syncthreads();
  if (j < NC) {
    float m = -1e30f;
    for (int k = 0; k < NC; k++) m = fmaxf(m, sl[k]);
    float s = 0.f;
    for (int k = 0; k < NC; k++) s += expf(sl[k] - m);
    out[g * NC + j] = sl[j] - m - logf(s);
  }
}

extern "C" void kernel_launch(void* const* d_in, const int* in_sizes, int n_in,
                              void* d_out, int out_size, void* d_ws,
                              size_t ws_size, hipStream_t stream) {
  const float* x   = (const float*)d_in[0];
  const int* edge  = (const int*)d_in[1];
  const int* batch = (const int*)d_in[2];
  const float* w1l = (const float*)d_in[3];
  const float* b1l = (const float*)d_in[4];
  const float* w1r = (const float*)d_in[5];
  const float* w2l = (const float*)d_in[6];
  const float* b2l = (const float*)d_in[7];
  const float* w2r = (const float*)d_in[8];
  const float* wfc = (const float*)d_in[9];
  const float* bfc = (const float*)d_in[10];
  float* out = (float*)d_out;

  const int* src = edge;
  const int* dst = edge + NE;

  const size_t NF = (size_t)NN * 64;
  // zero region: cnt[NN] + poolA[4096] + poolB[4096] + poolCnt[64]
  int*   cnt     = (int*)d_ws;
  float* poolA   = (float*)(cnt + NN);
  float* poolB   = poolA + (size_t)NG * 64;
  float* poolCnt = poolB + (size_t)NG * 64;
  int*   cursor  = (int*)(poolCnt + NG);
  int*   rowptr  = cursor + NN;            // [NN+1] padded to 50004
  int*   ssrc    = rowptr + 50004;
  int*   bsum    = ssrc + NE;              // [256]
  short* xwl     = (short*)(bsum + 256);   // bf16 [NN][64]
  short* h1s     = xwl + NF;               // bf16 [NN][64]
  float* xwr     = (float*)(h1s + NF);     // f32  [NN][64]
  float* agg2    = xwr + NF;               // f32  [NN][64]
  short* wbt     = (short*)(agg2 + NF);    // bf16 [128][512]

  hipMemsetAsync(cnt, 0, (NN + 2 * NG * 64 + NG) * sizeof(int), stream);

  hist_kernel<<<(NE + 255) / 256, 256, 0, stream>>>(dst, cnt);
  scan1_kernel<<<SCAN_BLOCKS, 256, 0, stream>>>(cnt, rowptr, bsum);
  scan2_kernel<<<1, 256, 0, stream>>>(bsum);
  scan3_kernel<<<SCAN_BLOCKS, 256, 0, stream>>>(bsum, rowptr, cursor);
  scatter_kernel<<<(NE + 255) / 256, 256, 0, stream>>>(src, dst, cursor, ssrc);

  wbt_prep_kernel<<<65536 / 256, 256, 0, stream>>>(w1l, w1r, wbt);
  gemm1_mfma_kernel<<<(NN + 63) / 64, 256, 0, stream>>>(x, wbt, xwl, xwr);

  agg1_h1_kernel<<<(NN + 3) / 4, 256, 0, stream>>>(rowptr, ssrc, xwl, xwr, b1l, h1s);
  agg2_kernel<<<(NN + 3) / 4, 256, 0, stream>>>(rowptr, ssrc, h1s, agg2);
  pool1_kernel<<<SCAN_BLOCKS, 256, 0, stream>>>(batch, agg2, h1s, rowptr, poolA, poolB, poolCnt);
  final_kernel<<<NG, 128, 0, stream>>>(poolA, poolB, poolCnt, w2l, w2r, b2l, wfc, bfc, out);
}